// Round 1
// baseline (8765.995 us; speedup 1.0000x reference)
//
#include <hip/hip_runtime.h>
#include <hip/hip_bf16.h>
#include <cstdint>

#define B_Q   2048
#define N_K   131072
#define KDIM  256
#define VDIM  256
#define TOPK  8
#define NCH   32            // key chunks
#define CH    (N_K / NCH)   // 4096 keys per chunk
#define BQ    32            // queries per block (phase1)
#define KT    64            // keys staged per tile
#define DSL   64            // d-slice staged per iteration
#define QSTRIDE 260         // padded LDS stride (floats) for query tile
#define KSTRIDE 68          // padded LDS stride (floats) for key slice

__device__ __forceinline__ bool lex_lt(float d1, int i1, float d2, int i2) {
    return (d1 < d2) || (d1 == d2 && i1 < i2);
}

// sorted insert into ascending-lex top-8 kept in registers
__device__ __forceinline__ void ins8(float s, int i, float (&d)[TOPK], int (&x)[TOPK]) {
    if (!lex_lt(s, i, d[TOPK - 1], x[TOPK - 1])) return;
    d[TOPK - 1] = s; x[TOPK - 1] = i;
    #pragma unroll
    for (int p = TOPK - 1; p > 0; --p) {
        if (lex_lt(d[p], x[p], d[p - 1], x[p - 1])) {
            float td = d[p]; d[p] = d[p - 1]; d[p - 1] = td;
            int   ti = x[p]; x[p] = x[p - 1]; x[p - 1] = ti;
        }
    }
}

// ||row||^2 for each row of an [rows x 256] f32 matrix; one wave per row
__global__ void sq_norms_kernel(const float* __restrict__ x, float* __restrict__ out, int rows) {
    int gw   = (blockIdx.x * blockDim.x + threadIdx.x) >> 6;
    int lane = threadIdx.x & 63;
    if (gw >= rows) return;
    float4 v = reinterpret_cast<const float4*>(x + (size_t)gw * KDIM)[lane];
    float s = v.x * v.x + v.y * v.y + v.z * v.z + v.w * v.w;
    #pragma unroll
    for (int off = 32; off > 0; off >>= 1) s += __shfl_down(s, off, 64);
    if (lane == 0) out[gw] = s;
}

// phase 1: per (query-tile, key-chunk) block -> top-8 candidates per query
__global__ __launch_bounds__(256, 3) void phase1_kernel(
    const float* __restrict__ query, const float* __restrict__ keys,
    const float* __restrict__ q2g, const float* __restrict__ k2g,
    float* __restrict__ cdist, int* __restrict__ cidx) {

    __shared__ float qs[BQ * QSTRIDE];   // 33.3 KB (reused as merge buffer)
    __shared__ float ks[KT * KSTRIDE];   // 17.4 KB

    const int tid     = threadIdx.x;
    const int chunk   = blockIdx.x;
    const int qt      = blockIdx.y;
    const int q0_base = qt * BQ;
    const int kbase   = chunk * CH;

    // stage full query tile: BQ x 256 floats
    for (int f = tid; f < BQ * KDIM / 4; f += 256) {
        int row = f >> 6;      // 64 float4 per row
        int c4  = f & 63;
        float4 v = reinterpret_cast<const float4*>(query + (size_t)(q0_base + row) * KDIM)[c4];
        *reinterpret_cast<float4*>(&qs[row * QSTRIDE + c4 * 4]) = v;
    }
    __syncthreads();

    const int qg = tid >> 4;        // 0..15
    const int kg = tid & 15;        // 0..15
    const int qa = qg, qb = qg + 16;
    const float q2a = q2g[q0_base + qa];
    const float q2b = q2g[q0_base + qb];

    float td[2][TOPK]; int ti[2][TOPK];
    #pragma unroll
    for (int s = 0; s < TOPK; ++s) {
        td[0][s] = INFINITY; td[1][s] = INFINITY;
        ti[0][s] = 0x7fffffff; ti[1][s] = 0x7fffffff;
    }

    for (int kt = 0; kt < CH; kt += KT) {
        float acc[2][4][4];
        #pragma unroll
        for (int a = 0; a < 2; ++a)
            #pragma unroll
            for (int j = 0; j < 4; ++j)
                #pragma unroll
                for (int c = 0; c < 4; ++c) acc[a][j][c] = 0.0f;

        for (int ds = 0; ds < KDIM; ds += DSL) {
            __syncthreads();
            // stage ks[KT][DSL]
            for (int f = tid; f < KT * DSL / 4; f += 256) {
                int row = f >> 4;   // 16 float4 per row
                int c4  = f & 15;
                float4 v = reinterpret_cast<const float4*>(
                    keys + (size_t)(kbase + kt + row) * KDIM + ds)[c4];
                *reinterpret_cast<float4*>(&ks[row * KSTRIDE + c4 * 4]) = v;
            }
            __syncthreads();

            #pragma unroll
            for (int dd = 0; dd < DSL; dd += 4) {
                float4 qva = *reinterpret_cast<const float4*>(&qs[qa * QSTRIDE + ds + dd]);
                float4 qvb = *reinterpret_cast<const float4*>(&qs[qb * QSTRIDE + ds + dd]);
                #pragma unroll
                for (int j = 0; j < 4; ++j) {
                    float4 kv = *reinterpret_cast<const float4*>(&ks[(kg + 16 * j) * KSTRIDE + dd]);
                    acc[0][j][0] += qva.x * kv.x; acc[0][j][1] += qva.y * kv.y;
                    acc[0][j][2] += qva.z * kv.z; acc[0][j][3] += qva.w * kv.w;
                    acc[1][j][0] += qvb.x * kv.x; acc[1][j][1] += qvb.y * kv.y;
                    acc[1][j][2] += qvb.z * kv.z; acc[1][j][3] += qvb.w * kv.w;
                }
            }
        }
        // finalize 8 dots of this tile
        #pragma unroll
        for (int j = 0; j < 4; ++j) {
            int   ki  = kbase + kt + kg + 16 * j;
            float k2v = k2g[ki];
            float da  = (acc[0][j][0] + acc[0][j][1]) + (acc[0][j][2] + acc[0][j][3]);
            float db  = (acc[1][j][0] + acc[1][j][1]) + (acc[1][j][2] + acc[1][j][3]);
            float sa  = fmaxf(q2a + k2v - 2.0f * da, 0.0f);
            float sb  = fmaxf(q2b + k2v - 2.0f * db, 0.0f);
            ins8(sa, ki, td[0], ti[0]);
            ins8(sb, ki, td[1], ti[1]);
        }
    }

    // block merge: 16 threads' top-8 -> per-query top-8 (reuse qs as buffer)
    __syncthreads();
    float* cb_d = qs;                                      // 4096 floats
    int*   cb_i = reinterpret_cast<int*>(qs + BQ * 16 * TOPK);
    #pragma unroll
    for (int h = 0; h < 2; ++h) {
        int q = qg + 16 * h;
        #pragma unroll
        for (int s = 0; s < TOPK; ++s) {
            cb_d[(q * 16 + kg) * TOPK + s] = td[h][s];
            cb_i[(q * 16 + kg) * TOPK + s] = ti[h][s];
        }
    }
    __syncthreads();

    if (tid < BQ) {
        float md[TOPK]; int mi[TOPK];
        #pragma unroll
        for (int s = 0; s < TOPK; ++s) { md[s] = INFINITY; mi[s] = 0x7fffffff; }
        for (int j = 0; j < 16 * TOPK; ++j) {
            ins8(cb_d[tid * 16 * TOPK + j], cb_i[tid * 16 * TOPK + j], md, mi);
        }
        size_t off = ((size_t)(q0_base + tid) * NCH + chunk) * TOPK;
        #pragma unroll
        for (int s = 0; s < TOPK; ++s) { cdist[off + s] = md[s]; cidx[off + s] = mi[s]; }
    }
}

// phase 2: merge NCH*8 candidates per query, gather vals rows
__global__ void phase2_kernel(const float* __restrict__ cdist, const int* __restrict__ cidx,
                              const float* __restrict__ vals, float* __restrict__ out) {
    const int lane = threadIdx.x & 63;
    const int q    = blockIdx.x * 4 + (threadIdx.x >> 6);
    const int C    = NCH * TOPK;   // 256 candidates

    float4 cd = reinterpret_cast<const float4*>(cdist + (size_t)q * C)[lane];
    int4   ci = reinterpret_cast<const int4*>(cidx + (size_t)q * C)[lane];
    float d[4] = {cd.x, cd.y, cd.z, cd.w};
    int   x[4] = {ci.x, ci.y, ci.z, ci.w};

    int res[TOPK];
    #pragma unroll
    for (int r = 0; r < TOPK; ++r) {
        float bd = d[0]; int bi = x[0];
        #pragma unroll
        for (int j = 1; j < 4; ++j) if (lex_lt(d[j], x[j], bd, bi)) { bd = d[j]; bi = x[j]; }
        #pragma unroll
        for (int off = 32; off > 0; off >>= 1) {
            float od = __shfl_xor(bd, off, 64);
            int   oi = __shfl_xor(bi, off, 64);
            if (lex_lt(od, oi, bd, bi)) { bd = od; bi = oi; }
        }
        res[r] = bi;
        #pragma unroll
        for (int j = 0; j < 4; ++j) if (x[j] == bi) d[j] = INFINITY;
    }

    #pragma unroll
    for (int r = 0; r < TOPK; ++r) {
        float4 v = reinterpret_cast<const float4*>(vals + (size_t)res[r] * VDIM)[lane];
        reinterpret_cast<float4*>(out + ((size_t)q * TOPK + r) * VDIM)[lane] = v;
    }
}

extern "C" void kernel_launch(void* const* d_in, const int* in_sizes, int n_in,
                              void* d_out, int out_size, void* d_ws, size_t ws_size,
                              hipStream_t stream) {
    const float* query = (const float*)d_in[0];
    const float* keys  = (const float*)d_in[1];
    const float* vals  = (const float*)d_in[2];
    // d_in[3] = top_k scalar (always 8) — compile-time constant here
    float* out = (float*)d_out;

    float* q2    = (float*)d_ws;                       // 2048
    float* k2    = q2 + B_Q;                           // 131072
    float* cdist = k2 + N_K;                           // B_Q*NCH*TOPK = 524288
    int*   cidx  = (int*)(cdist + (size_t)B_Q * NCH * TOPK);

    sq_norms_kernel<<<B_Q / 4, 256, 0, stream>>>(query, q2, B_Q);
    sq_norms_kernel<<<N_K / 4, 256, 0, stream>>>(keys, k2, N_K);

    dim3 g1(NCH, B_Q / BQ);
    phase1_kernel<<<g1, 256, 0, stream>>>(query, keys, q2, k2, cdist, cidx);

    phase2_kernel<<<B_Q / 4, 256, 0, stream>>>(cdist, cidx, vals, out);
}

// Round 2
// 369.624 us; speedup vs baseline: 23.7160x; 23.7160x over previous
//
#include <hip/hip_runtime.h>
#include <hip/hip_bf16.h>
#include <cstdint>

#define B_Q   2048
#define N_K   131072
#define KD    256
#define VD    256
#define TOPK  8

#define DQ      288            // augmented dim: 256 + [k2_hi, k2_lo, bias, 0...]
#define SSTEPS  9              // DQ / 32
#define TK      64             // keys per tile
#define TILE_B  (TK * DQ * 2)  // 36864 bytes per permuted tile
#define NCHUNK  32
#define CHUNK   (N_K / NCHUNK) // 4096
#define CTILES  (CHUNK / TK)   // 64
#define QB      128            // queries per phase-1 block
#define QTILES  (B_Q / QB)     // 16

typedef short bf16x8 __attribute__((ext_vector_type(8)));
typedef float f32x4  __attribute__((ext_vector_type(4)));

__device__ __forceinline__ unsigned short f2bf(float x) {
    uint32_t u = __float_as_uint(x);
    uint32_t r = (u + 0x7FFFu + ((u >> 16) & 1u)) >> 16;
    return (unsigned short)r;
}

__device__ __forceinline__ bool lex_lt(float d1, int i1, float d2, int i2) {
    return (d1 < d2) || (d1 == d2 && i1 < i2);
}

__device__ __forceinline__ void gld16(const void* g, void* l) {
    __builtin_amdgcn_global_load_lds(
        (const __attribute__((address_space(1))) unsigned int*)g,
        (__attribute__((address_space(3))) unsigned int*)l, 16, 0, 0);
}

__device__ __forceinline__ void ins8u(uint32_t v, uint32_t (&c)[8]) {
    if (v < c[7]) {
        c[7] = v;
        #pragma unroll
        for (int p = 7; p > 0; --p)
            if (c[p] < c[p - 1]) { uint32_t t = c[p]; c[p] = c[p - 1]; c[p - 1] = t; }
    }
}

__device__ __forceinline__ void ins16u(uint32_t v, uint32_t (&c)[16]) {
    if (v < c[15]) {
        c[15] = v;
        #pragma unroll
        for (int p = 15; p > 0; --p)
            if (c[p] < c[p - 1]) { uint32_t t = c[p]; c[p] = c[p - 1]; c[p - 1] = t; }
    }
}

// ||row||^2 for each row of an [rows x 256] f32 matrix; one wave per row
__global__ void sq_norms_kernel(const float* __restrict__ x, float* __restrict__ out, int rows) {
    int gw   = (blockIdx.x * blockDim.x + threadIdx.x) >> 6;
    int lane = threadIdx.x & 63;
    if (gw >= rows) return;
    float4 v = reinterpret_cast<const float4*>(x + (size_t)gw * KD)[lane];
    float s = v.x * v.x + v.y * v.y + v.z * v.z + v.w * v.w;
    #pragma unroll
    for (int off = 32; off > 0; off >>= 1) s += __shfl_down(s, off, 64);
    if (lane == 0) out[gw] = s;
}

// queries -> augmented bf16 [B_Q][288]: [-2q, 1, 1, 1, 0...]
__global__ void qaug_kernel(const float* __restrict__ q, unsigned short* __restrict__ qa) {
    int qi = blockIdx.x, t = threadIdx.x;
    if (t < 256) {
        qa[qi * DQ + t] = f2bf(-2.0f * q[(size_t)qi * KD + t]);
    } else if (t < DQ) {
        int d = t - 256;
        qa[qi * DQ + t] = (d < 3) ? f2bf(1.0f) : 0;
    }
}

// keys -> bf16, augmented with [k2_hi, k2_lo, 256.0], permuted into MFMA
// fragment-stream order: [tile][s][ki][lane][8 bf16]
__global__ void kperm_kernel(const float* __restrict__ keys, const float* __restrict__ k2g,
                             unsigned short* __restrict__ kp) {
    size_t o = (size_t)blockIdx.x * 256 + threadIdx.x;   // < 2048*9*4*64
    int l    = (int)(o & 63);
    int ki   = (int)((o >> 6) & 3);
    int rem  = (int)(o >> 8);
    int s    = rem % 9;
    int tile = rem / 9;
    int r    = tile * 64 + ki * 16 + (l & 15);
    int g    = l >> 4;
    unsigned short u[8];
    if (s < 8) {
        const float* src = keys + (size_t)r * KD + s * 32 + g * 8;
        #pragma unroll
        for (int e = 0; e < 8; ++e) u[e] = f2bf(src[e]);
    } else {
        #pragma unroll
        for (int e = 0; e < 8; ++e) u[e] = 0;
        if (g == 0) {
            float k2 = k2g[r];
            unsigned short hi = f2bf(k2);
            float hf = __uint_as_float(((uint32_t)hi) << 16);
            u[0] = hi;
            u[1] = f2bf(k2 - hf);
            u[2] = 0x4380;   // bf16(256.0)
        }
    }
    uint4 pack;
    pack.x = (uint32_t)u[0] | ((uint32_t)u[1] << 16);
    pack.y = (uint32_t)u[2] | ((uint32_t)u[3] << 16);
    pack.z = (uint32_t)u[4] | ((uint32_t)u[5] << 16);
    pack.w = (uint32_t)u[6] | ((uint32_t)u[7] << 16);
    *reinterpret_cast<uint4*>(kp + o * 8) = pack;
}

// phase 1: MFMA coarse scores + per-(q,chunk) top-16 packed candidates
__global__ __launch_bounds__(256, 2) void phase1_kernel(
    const unsigned short* __restrict__ qaug, const char* __restrict__ kperm,
    uint32_t* __restrict__ cand) {

    __shared__ __align__(16) char lds[2][TILE_B];   // 73728 B

    const int tid   = threadIdx.x;
    const int w     = tid >> 6;
    const int l     = tid & 63;
    const int b     = blockIdx.x;
    const int chunk = b & (NCHUNK - 1);
    const int qt    = b >> 5;
    const int q0    = qt * QB;
    const char* kpb = kperm + (size_t)chunk * CTILES * TILE_B;

    // Q fragments in registers: 2 qfrags x 9 steps
    bf16x8 af[2][SSTEPS];
    #pragma unroll
    for (int qf = 0; qf < 2; ++qf)
        #pragma unroll
        for (int s = 0; s < SSTEPS; ++s) {
            int qr = q0 + w * 32 + qf * 16 + (l & 15);
            af[qf][s] = *reinterpret_cast<const bf16x8*>(qaug + (size_t)qr * DQ + s * 32 + (l >> 4) * 8);
        }

    uint32_t cnd[2][4][8];
    #pragma unroll
    for (int qf = 0; qf < 2; ++qf)
        #pragma unroll
        for (int j = 0; j < 4; ++j)
            #pragma unroll
            for (int s = 0; s < 8; ++s) cnd[qf][j][s] = 0xFFFFFFFFu;

    // stage tile t into buf: 36 segments of 1024 B; wave w takes segs w, w+4, ...
    auto STAGE = [&](int t, int buf) {
        const char* src = kpb + (size_t)t * TILE_B;
        #pragma unroll
        for (int i = 0; i < 9; ++i) {
            int seg = i * 4 + w;
            gld16(src + seg * 1024 + l * 16, &lds[buf][seg * 1024]);
        }
    };

    STAGE(0, 0);
    __syncthreads();

    for (int t = 0; t < CTILES; ++t) {
        int cur = t & 1;
        if (t + 1 < CTILES) STAGE(t + 1, cur ^ 1);

        f32x4 acc[2][4];
        #pragma unroll
        for (int qf = 0; qf < 2; ++qf)
            #pragma unroll
            for (int ki = 0; ki < 4; ++ki) acc[qf][ki] = (f32x4){0.f, 0.f, 0.f, 0.f};

        const char* lb = &lds[cur][0];
        #pragma unroll
        for (int s = 0; s < SSTEPS; ++s) {
            bf16x8 bfr[4];
            #pragma unroll
            for (int ki = 0; ki < 4; ++ki)
                bfr[ki] = *reinterpret_cast<const bf16x8*>(lb + ((s * 4 + ki) * 64 + l) * 16);
            #pragma unroll
            for (int ki = 0; ki < 4; ++ki) {
                acc[0][ki] = __builtin_amdgcn_mfma_f32_16x16x32_bf16(af[0][s], bfr[ki], acc[0][ki], 0, 0, 0);
                acc[1][ki] = __builtin_amdgcn_mfma_f32_16x16x32_bf16(af[1][s], bfr[ki], acc[1][ki], 0, 0, 0);
            }
        }

        // selection: scores are positive -> uint-monotone packing
        uint32_t bl = (uint32_t)(t * 64 + (l & 15));
        #pragma unroll
        for (int qf = 0; qf < 2; ++qf)
            #pragma unroll
            for (int j = 0; j < 4; ++j) {
                uint32_t p0 = (__float_as_uint(acc[qf][0][j]) & 0xFFFFE000u) | bl;
                uint32_t p1 = (__float_as_uint(acc[qf][1][j]) & 0xFFFFE000u) | (bl + 16u);
                uint32_t p2 = (__float_as_uint(acc[qf][2][j]) & 0xFFFFE000u) | (bl + 32u);
                uint32_t p3 = (__float_as_uint(acc[qf][3][j]) & 0xFFFFE000u) | (bl + 48u);
                uint32_t m = min(min(p0, p1), min(p2, p3));
                if (m < cnd[qf][j][7]) {
                    ins8u(p0, cnd[qf][j]); ins8u(p1, cnd[qf][j]);
                    ins8u(p2, cnd[qf][j]); ins8u(p3, cnd[qf][j]);
                }
            }
        __syncthreads();
    }

    // merge 16 lanes x top-8 -> per-q top-16 (reuse LDS)
    uint32_t* mrg = reinterpret_cast<uint32_t*>(&lds[0][0]);   // 128*16*8 u32 = 64 KB
    #pragma unroll
    for (int qf = 0; qf < 2; ++qf)
        #pragma unroll
        for (int j = 0; j < 4; ++j) {
            int qrow = w * 32 + qf * 16 + (l >> 4) * 4 + j;
            int col  = l & 15;
            #pragma unroll
            for (int s = 0; s < 8; ++s)
                mrg[(qrow * 16 + col) * 8 + s] = cnd[qf][j][s];
        }
    __syncthreads();
    if (tid < QB) {
        uint32_t best[16];
        #pragma unroll
        for (int s = 0; s < 16; ++s) best[s] = 0xFFFFFFFFu;
        for (int i = 0; i < 128; ++i)
            ins16u(mrg[tid * 128 + ((i + tid) & 127)], best);
        uint32_t* dst = cand + ((size_t)(q0 + tid) * NCHUNK + chunk) * 16;
        #pragma unroll
        for (int s = 0; s < 16; ++s) dst[s] = best[s];
    }
}

// phase 2: top-32 of 512 packed cands, exact f32 rescore, lex top-8, gather
__global__ __launch_bounds__(256) void phase2_kernel(
    const uint32_t* __restrict__ cand, const float* __restrict__ query,
    const float* __restrict__ keys, const float* __restrict__ q2g,
    const float* __restrict__ k2g, const float* __restrict__ vals,
    float* __restrict__ out) {

    __shared__ uint32_t cp[512];
    __shared__ int topg[32];
    __shared__ float td2[32];
    __shared__ int fin[8];

    const int q = blockIdx.x, tid = threadIdx.x, w = tid >> 6, l = tid & 63;
    cp[tid]       = cand[(size_t)q * 512 + tid];
    cp[tid + 256] = cand[(size_t)q * 512 + tid + 256];
    __syncthreads();

    if (w == 0) {   // one wave extracts global coarse top-32
        uint32_t v[8]; int pos[8];
        #pragma unroll
        for (int j = 0; j < 8; ++j) { v[j] = cp[l * 8 + j]; pos[j] = l * 8 + j; }
        for (int r = 0; r < 32; ++r) {
            uint32_t bv = v[0]; int bp = pos[0];
            #pragma unroll
            for (int j = 1; j < 8; ++j) if (v[j] < bv) { bv = v[j]; bp = pos[j]; }
            #pragma unroll
            for (int off = 32; off > 0; off >>= 1) {
                uint32_t ov = __shfl_xor(bv, off, 64);
                int      op = __shfl_xor(bp, off, 64);
                if (ov < bv) { bv = ov; bp = op; }
            }
            if (l == 0) topg[r] = (bp >> 4) * CHUNK + (int)(bv & 0x1FFFu);
            #pragma unroll
            for (int j = 0; j < 8; ++j) if (pos[j] == bp) v[j] = 0xFFFFFFFFu;
        }
    }
    __syncthreads();

    float4 qv = reinterpret_cast<const float4*>(query + (size_t)q * KD)[l];
    for (int r = w; r < 32; r += 4) {
        int gk = topg[r];
        float4 kv = reinterpret_cast<const float4*>(keys + (size_t)gk * KD)[l];
        float d = qv.x * kv.x + qv.y * kv.y + qv.z * kv.z + qv.w * kv.w;
        #pragma unroll
        for (int off = 32; off > 0; off >>= 1) d += __shfl_down(d, off, 64);
        if (l == 0) td2[r] = fmaxf(q2g[q] + k2g[gk] - 2.0f * d, 0.0f);
    }
    __syncthreads();

    if (tid == 0) {
        float fd[8]; int fi[8];
        #pragma unroll
        for (int s = 0; s < 8; ++s) { fd[s] = INFINITY; fi[s] = 0x7fffffff; }
        for (int i = 0; i < 32; ++i) {
            float d2 = td2[i]; int gk = topg[i];
            if (lex_lt(d2, gk, fd[7], fi[7])) {
                fd[7] = d2; fi[7] = gk;
                #pragma unroll
                for (int p = 7; p > 0; --p)
                    if (lex_lt(fd[p], fi[p], fd[p - 1], fi[p - 1])) {
                        float t1 = fd[p]; fd[p] = fd[p - 1]; fd[p - 1] = t1;
                        int   t2 = fi[p]; fi[p] = fi[p - 1]; fi[p - 1] = t2;
                    }
            }
        }
        #pragma unroll
        for (int s = 0; s < 8; ++s) fin[s] = fi[s];
    }
    __syncthreads();

    for (int r = w; r < TOPK; r += 4) {
        float4 v = reinterpret_cast<const float4*>(vals + (size_t)fin[r] * VD)[l];
        reinterpret_cast<float4*>(out + ((size_t)q * TOPK + r) * VD)[l] = v;
    }
}

extern "C" void kernel_launch(void* const* d_in, const int* in_sizes, int n_in,
                              void* d_out, int out_size, void* d_ws, size_t ws_size,
                              hipStream_t stream) {
    const float* query = (const float*)d_in[0];
    const float* keys  = (const float*)d_in[1];
    const float* vals  = (const float*)d_in[2];
    float* out = (float*)d_out;

    char* ws = (char*)d_ws;
    float*          q2    = (float*)(ws);                              // 8 KB
    float*          k2    = (float*)(ws + 8192);                       // 512 KB
    unsigned short* qaug  = (unsigned short*)(ws + 532480);            // 1.125 MB
    unsigned short* kperm = (unsigned short*)(ws + 1712128);           // 72 MB
    uint32_t*       cand  = (uint32_t*)(ws + 77209600);                // 4 MB (ends ~81.4 MB)

    sq_norms_kernel<<<B_Q / 4, 256, 0, stream>>>(query, q2, B_Q);
    sq_norms_kernel<<<N_K / 4, 256, 0, stream>>>(keys, k2, N_K);
    qaug_kernel<<<B_Q, 320, 0, stream>>>(query, qaug);
    kperm_kernel<<<(N_K / TK) * SSTEPS * 4 * 64 / 256, 256, 0, stream>>>(keys, k2, kperm);
    phase1_kernel<<<NCHUNK * QTILES, 256, 0, stream>>>(qaug, (const char*)kperm, cand);
    phase2_kernel<<<B_Q, 256, 0, stream>>>(cand, query, keys, q2, k2, vals, out);
}

// Round 4
// 344.392 us; speedup vs baseline: 25.4535x; 1.0733x over previous
//
#include <hip/hip_runtime.h>
#include <hip/hip_bf16.h>
#include <cstdint>

#define B_Q    2048
#define N_K    131072
#define KD     256
#define VD     256
#define TOPK   8

#define TK     64                 // keys per tile
#define NCHUNK 32
#define CHUNK  (N_K / NCHUNK)     // 4096
#define CTILES (CHUNK / TK)       // 64
#define QB     256                // queries per phase-1 block (8 waves)
#define QTILES (B_Q / QB)         // 8
#define NBUF   4
#define TILE_B (TK * KD * 2)      // 32768 B per permuted tile
#define SSTEPS 8                  // 256 / 32
#define SENT   0x7F801FFFu        // packed sentinel: +INF score bits | idx 0x1FFF

typedef short bf16x8 __attribute__((ext_vector_type(8)));
typedef float f32x4  __attribute__((ext_vector_type(4)));

__device__ __forceinline__ unsigned short f2bf(float x) {
    uint32_t u = __float_as_uint(x);
    uint32_t r = (u + 0x7FFFu + ((u >> 16) & 1u)) >> 16;
    return (unsigned short)r;
}

__device__ __forceinline__ bool lex_lt(float d1, int i1, float d2, int i2) {
    return (d1 < d2) || (d1 == d2 && i1 < i2);
}

__device__ __forceinline__ uint32_t umin32(uint32_t a, uint32_t b) { return a < b ? a : b; }
__device__ __forceinline__ uint32_t umax32(uint32_t a, uint32_t b) { return a > b ? a : b; }

__device__ __forceinline__ void gld16(const void* g, void* l) {
    __builtin_amdgcn_global_load_lds(
        (const __attribute__((address_space(1))) unsigned int*)g,
        (__attribute__((address_space(3))) unsigned int*)l, 16, 0, 0);
}
__device__ __forceinline__ void gld4(const void* g, void* l) {
    __builtin_amdgcn_global_load_lds(
        (const __attribute__((address_space(1))) unsigned int*)g,
        (__attribute__((address_space(3))) unsigned int*)l, 4, 0, 0);
}

__device__ __forceinline__ void ins8u(uint32_t v, uint32_t (&c)[8]) {
    if (v < c[7]) {
        c[7] = v;
        #pragma unroll
        for (int p = 7; p > 0; --p)
            if (c[p] < c[p - 1]) { uint32_t t = c[p]; c[p] = c[p - 1]; c[p - 1] = t; }
    }
}

// queries: q2 (exact) + augmented bf16 [-2q] rows
__global__ void qprep_kernel(const float* __restrict__ q, float* __restrict__ q2,
                             unsigned short* __restrict__ qa) {
    int gw   = (blockIdx.x * blockDim.x + threadIdx.x) >> 6;
    int lane = threadIdx.x & 63;
    float4 v = reinterpret_cast<const float4*>(q + (size_t)gw * KD)[lane];
    float s = v.x * v.x + v.y * v.y + v.z * v.z + v.w * v.w;
    #pragma unroll
    for (int off = 32; off > 0; off >>= 1) s += __shfl_down(s, off, 64);
    if (lane == 0) q2[gw] = s;
    ushort4 u;
    u.x = f2bf(-2.f * v.x); u.y = f2bf(-2.f * v.y);
    u.z = f2bf(-2.f * v.z); u.w = f2bf(-2.f * v.w);
    *reinterpret_cast<ushort4*>(qa + (size_t)gw * KD + lane * 4) = u;
}

// keys: k2 exact (phase2) + k2b = k2 + 256 (phase1 coarse score bias;
// keeps score positive with ~12-sigma margin, exponent <= 2^9 so the
// 19-bit packed quantization granularity stays <= 0.5)
__global__ void kprep_kernel(const float* __restrict__ k, float* __restrict__ k2,
                             float* __restrict__ k2b) {
    int gw   = (blockIdx.x * blockDim.x + threadIdx.x) >> 6;
    int lane = threadIdx.x & 63;
    float4 v = reinterpret_cast<const float4*>(k + (size_t)gw * KD)[lane];
    float s = v.x * v.x + v.y * v.y + v.z * v.z + v.w * v.w;
    #pragma unroll
    for (int off = 32; off > 0; off >>= 1) s += __shfl_down(s, off, 64);
    if (lane == 0) { k2[gw] = s; k2b[gw] = s + 256.0f; }
}

// keys -> bf16, permuted into MFMA fragment-stream order:
// unit o = ((gtile*8 + s)*4 + ki)*64 + lane, 16 B each
__global__ void kperm_kernel(const float* __restrict__ keys, unsigned short* __restrict__ kp) {
    size_t o = (size_t)blockIdx.x * 256 + threadIdx.x;
    int l    = (int)(o & 63);
    size_t rem = o >> 6;
    int ki   = (int)(rem & 3);
    int s    = (int)((rem >> 2) & 7);
    int gt   = (int)(rem >> 5);
    int r    = gt * TK + ki * 16 + (l & 15);
    int d    = s * 32 + (l >> 4) * 8;
    const float* src = keys + (size_t)r * KD + d;
    unsigned short u[8];
    #pragma unroll
    for (int e = 0; e < 8; ++e) u[e] = f2bf(src[e]);
    uint4 pack;
    pack.x = (uint32_t)u[0] | ((uint32_t)u[1] << 16);
    pack.y = (uint32_t)u[2] | ((uint32_t)u[3] << 16);
    pack.z = (uint32_t)u[4] | ((uint32_t)u[5] << 16);
    pack.w = (uint32_t)u[6] | ((uint32_t)u[7] << 16);
    *reinterpret_cast<uint4*>(kp + o * 8) = pack;
}

// phase 1: MFMA coarse scores (k2+256-2qk), counted-vmcnt 3-deep pipeline,
// per-(q,chunk) 2x top-8 packed candidates via shuffle merge.
// Packed values are UNIQUE within a chunk (distinct 13-bit local idx), so all
// phase-1 comparisons/merges are tie-free.
__global__ __launch_bounds__(512, 2) void phase1_kernel(
    const unsigned short* __restrict__ qaug, const char* __restrict__ kperm,
    const float* __restrict__ k2b, uint32_t* __restrict__ cand) {

    __shared__ __align__(16) char  lds[NBUF][TILE_B];   // 128 KiB
    __shared__ __align__(16) float k2l[NBUF][TK];       // 1 KiB

    const int tid   = threadIdx.x;
    const int w     = tid >> 6;
    const int l     = tid & 63;
    const int l15   = l & 15;
    const int l4    = l >> 4;
    const int chunk = blockIdx.x & (NCHUNK - 1);
    const int qt    = blockIdx.x >> 5;
    const int q0    = qt * QB;
    const char*  kpb = kperm + (size_t)chunk * ((size_t)CTILES * TILE_B);
    const float* k2c = k2b + (size_t)chunk * CHUNK;

    // A fragments in registers: 2 qfrags x 8 steps (each wave owns 32 queries)
    bf16x8 af[2][SSTEPS];
    #pragma unroll
    for (int qf = 0; qf < 2; ++qf)
        #pragma unroll
        for (int s = 0; s < SSTEPS; ++s) {
            int qr = q0 + w * 32 + qf * 16 + l15;
            af[qf][s] = *reinterpret_cast<const bf16x8*>(
                qaug + (size_t)qr * KD + s * 32 + l4 * 8);
        }

    uint32_t cnd[2][4][8];
    #pragma unroll
    for (int qf = 0; qf < 2; ++qf)
        #pragma unroll
        for (int j = 0; j < 4; ++j)
            #pragma unroll
            for (int s = 0; s < 8; ++s) cnd[qf][j][s] = SENT;

    // 5 vmem ops per wave per stage (uniform across waves for vmcnt counting)
    auto STAGE = [&](int t) {
        int buf = t & (NBUF - 1);
        const char* src = kpb + (size_t)t * TILE_B;
        #pragma unroll
        for (int i = 0; i < 4; ++i) {
            int seg = w * 4 + i;                       // 32 segs x 1024 B
            gld16(src + seg * 1024 + l * 16, &lds[buf][seg * 1024]);
        }
        gld4(k2c + t * TK + l, &k2l[buf][0]);          // 64 floats, dup per wave OK
    };

    STAGE(0); STAGE(1); STAGE(2);

    for (int t = 0; t < CTILES; ++t) {
        const int buf = t & (NBUF - 1);
        // drain exactly tile t's 5 ops; keep t+1,t+2 in flight across barrier
        if (t < CTILES - 2)       asm volatile("s_waitcnt vmcnt(10)" ::: "memory");
        else if (t == CTILES - 2) asm volatile("s_waitcnt vmcnt(5)"  ::: "memory");
        else                      asm volatile("s_waitcnt vmcnt(0)"  ::: "memory");
        __builtin_amdgcn_s_barrier();
        __builtin_amdgcn_sched_barrier(0);

        const char* lb = &lds[buf][0];
        float k2v[4];
        #pragma unroll
        for (int ki = 0; ki < 4; ++ki) k2v[ki] = k2l[buf][ki * 16 + l15];

        f32x4 acc[2][4];
        #pragma unroll
        for (int qf = 0; qf < 2; ++qf)
            #pragma unroll
            for (int ki = 0; ki < 4; ++ki) acc[qf][ki] = (f32x4){0.f, 0.f, 0.f, 0.f};

        #pragma unroll
        for (int s = 0; s < SSTEPS; ++s) {
            bf16x8 bfr[4];
            #pragma unroll
            for (int ki = 0; ki < 4; ++ki)
                bfr[ki] = *reinterpret_cast<const bf16x8*>(lb + ((s * 4 + ki) * 64 + l) * 16);
            #pragma unroll
            for (int ki = 0; ki < 4; ++ki) {
                acc[0][ki] = __builtin_amdgcn_mfma_f32_16x16x32_bf16(af[0][s], bfr[ki], acc[0][ki], 0, 0, 0);
                acc[1][ki] = __builtin_amdgcn_mfma_f32_16x16x32_bf16(af[1][s], bfr[ki], acc[1][ki], 0, 0, 0);
            }
        }

        const uint32_t bl = (uint32_t)(t * TK + l15);
        #pragma unroll
        for (int qf = 0; qf < 2; ++qf)
            #pragma unroll
            for (int j = 0; j < 4; ++j) {
                uint32_t p0 = (__float_as_uint(k2v[0] + acc[qf][0][j]) & 0xFFFFE000u) | bl;
                uint32_t p1 = (__float_as_uint(k2v[1] + acc[qf][1][j]) & 0xFFFFE000u) | (bl + 16u);
                uint32_t p2 = (__float_as_uint(k2v[2] + acc[qf][2][j]) & 0xFFFFE000u) | (bl + 32u);
                uint32_t p3 = (__float_as_uint(k2v[3] + acc[qf][3][j]) & 0xFFFFE000u) | (bl + 48u);
                uint32_t m  = umin32(umin32(p0, p1), umin32(p2, p3));
                if (m < cnd[qf][j][7]) {   // exact packed compare: no tie-drop
                    ins8u(p0, cnd[qf][j]); ins8u(p1, cnd[qf][j]);
                    ins8u(p2, cnd[qf][j]); ins8u(p3, cnd[qf][j]);
                }
            }

        if (t + 3 < CTILES) STAGE(t + 3);
    }

    // shuffle merge: 16 lanes x top-8 -> two 8-lane groups each holding top-8
    #pragma unroll
    for (int qf = 0; qf < 2; ++qf)
        #pragma unroll
        for (int j = 0; j < 4; ++j) {
            uint32_t c[8];
            #pragma unroll
            for (int s = 0; s < 8; ++s) c[s] = cnd[qf][j][s];
            #pragma unroll
            for (int mask = 1; mask <= 4; mask <<= 1) {
                uint32_t o[8], m[8];
                #pragma unroll
                for (int s = 0; s < 8; ++s)
                    o[s] = (uint32_t)__shfl_xor((int)c[s], mask, 64);
                #pragma unroll
                for (int s = 0; s < 8; ++s) m[s] = umin32(c[s], o[7 - s]);
                #define CX(a,b) { uint32_t lo = umin32(m[a], m[b]); uint32_t hi = umax32(m[a], m[b]); m[a] = lo; m[b] = hi; }
                CX(0,4) CX(1,5) CX(2,6) CX(3,7)
                CX(0,2) CX(1,3) CX(4,6) CX(5,7)
                CX(0,1) CX(2,3) CX(4,5) CX(6,7)
                #undef CX
                #pragma unroll
                for (int s = 0; s < 8; ++s) c[s] = m[s];
            }
            if ((l15 & 7) == 0) {
                int qrow = q0 + w * 32 + qf * 16 + l4 * 4 + j;
                uint32_t* dst = cand + ((size_t)qrow * NCHUNK + chunk) * 16 + (l15 & 8);
                uint4 a = {c[0], c[1], c[2], c[3]};
                uint4 b = {c[4], c[5], c[6], c[7]};
                *reinterpret_cast<uint4*>(dst)     = a;
                *reinterpret_cast<uint4*>(dst + 4) = b;
            }
        }
}

// phase 2: top-32 of 512 cands via UNIQUE 64-bit keys (quantized score | global
// idx) -- tie-proof across chunks; then exact f32 rescore, lex top-8, gather.
__global__ __launch_bounds__(256) void phase2_kernel(
    const uint32_t* __restrict__ cand, const float* __restrict__ query,
    const float* __restrict__ keys, const float* __restrict__ q2g,
    const float* __restrict__ k2g, const float* __restrict__ vals,
    float* __restrict__ out) {

    __shared__ uint32_t cp[512];
    __shared__ int topg[32];
    __shared__ float td2[32];
    __shared__ int fin[8];

    const int q = blockIdx.x, tid = threadIdx.x, w = tid >> 6, l = tid & 63;
    cp[tid]       = cand[(size_t)q * 512 + tid];
    cp[tid + 256] = cand[(size_t)q * 512 + tid + 256];
    __syncthreads();

    if (w == 0) {   // one wave extracts global coarse top-32 (unique keys)
        unsigned long long v[8];
        #pragma unroll
        for (int j = 0; j < 8; ++j) {
            int i = l * 8 + j;
            uint32_t p = cp[i];
            unsigned long long gk = (unsigned long long)((i >> 4) * CHUNK + (int)(p & 0x1FFFu));
            v[j] = ((unsigned long long)(p >> 13) << 17) | gk;
        }
        for (int r = 0; r < 32; ++r) {
            unsigned long long bv = v[0];
            #pragma unroll
            for (int j = 1; j < 8; ++j) if (v[j] < bv) bv = v[j];
            #pragma unroll
            for (int off = 32; off > 0; off >>= 1) {
                unsigned long long ov = __shfl_xor(bv, off, 64);
                if (ov < bv) bv = ov;
            }
            if (l == 0) topg[r] = (int)(bv & 0x1FFFFull);
            #pragma unroll
            for (int j = 0; j < 8; ++j) if (v[j] == bv) v[j] = ~0ull;
        }
    }
    __syncthreads();

    float4 qv = reinterpret_cast<const float4*>(query + (size_t)q * KD)[l];
    for (int r = w; r < 32; r += 4) {
        int gk = topg[r];
        float4 kv = reinterpret_cast<const float4*>(keys + (size_t)gk * KD)[l];
        float d = qv.x * kv.x + qv.y * kv.y + qv.z * kv.z + qv.w * kv.w;
        #pragma unroll
        for (int off = 32; off > 0; off >>= 1) d += __shfl_down(d, off, 64);
        if (l == 0) td2[r] = fmaxf(q2g[q] + k2g[gk] - 2.0f * d, 0.0f);
    }
    __syncthreads();

    if (tid == 0) {
        float fd[8]; int fi[8];
        #pragma unroll
        for (int s = 0; s < 8; ++s) { fd[s] = INFINITY; fi[s] = 0x7fffffff; }
        for (int i = 0; i < 32; ++i) {
            float d2 = td2[i]; int gk = topg[i];
            if (lex_lt(d2, gk, fd[7], fi[7])) {
                fd[7] = d2; fi[7] = gk;
                #pragma unroll
                for (int p = 7; p > 0; --p)
                    if (lex_lt(fd[p], fi[p], fd[p - 1], fi[p - 1])) {
                        float t1 = fd[p]; fd[p] = fd[p - 1]; fd[p - 1] = t1;
                        int   t2 = fi[p]; fi[p] = fi[p - 1]; fi[p - 1] = t2;
                    }
            }
        }
        #pragma unroll
        for (int s = 0; s < 8; ++s) fin[s] = fi[s];
    }
    __syncthreads();

    for (int r = w; r < TOPK; r += 4) {
        float4 v = reinterpret_cast<const float4*>(vals + (size_t)fin[r] * VD)[l];
        reinterpret_cast<float4*>(out + ((size_t)q * TOPK + r) * VD)[l] = v;
    }
}

extern "C" void kernel_launch(void* const* d_in, const int* in_sizes, int n_in,
                              void* d_out, int out_size, void* d_ws, size_t ws_size,
                              hipStream_t stream) {
    const float* query = (const float*)d_in[0];
    const float* keys  = (const float*)d_in[1];
    const float* vals  = (const float*)d_in[2];
    float* out = (float*)d_out;

    char* ws = (char*)d_ws;
    float*          q2    = (float*)(ws);                      // 8 KB
    float*          k2    = (float*)(ws + 8192);               // 512 KB
    float*          k2b   = (float*)(ws + 532480);             // 512 KB
    unsigned short* qaug  = (unsigned short*)(ws + 1056768);   // 1 MB
    unsigned short* kperm = (unsigned short*)(ws + 2105344);   // 64 MB
    uint32_t*       cand  = (uint32_t*)(ws + 69214208);        // 4 MB (end ~73 MB)

    qprep_kernel<<<B_Q / 4, 256, 0, stream>>>(query, q2, qaug);
    kprep_kernel<<<N_K / 4, 256, 0, stream>>>(keys, k2, k2b);
    kperm_kernel<<<(N_K / TK) * SSTEPS * 4 * 64 / 256, 256, 0, stream>>>(keys, kperm);
    phase1_kernel<<<NCHUNK * QTILES, 512, 0, stream>>>(qaug, (const char*)kperm, k2b, cand);
    phase2_kernel<<<B_Q, 256, 0, stream>>>(cand, query, keys, q2, k2, vals, out);
}